// Round 12
// baseline (107.161 us; speedup 1.0000x reference)
//
#include <hip/hip_runtime.h>
#include <hip/hip_bf16.h>
#include <math.h>

// Problem constants
#define P_TOTAL 18378
// param breakpoints (floats): w1 [0,400), b1 [400,416), w2 [416,13216),
// b2 [13216,13248), w3 [13248,18368), b3 [18368,18378)

typedef __attribute__((ext_vector_type(8))) short short8;
typedef __attribute__((ext_vector_type(4))) float float4v;
typedef __attribute__((ext_vector_type(16))) float float16;

__device__ __forceinline__ unsigned short f2bf(float f) {
    union { float f; unsigned u; } v; v.f = f;
    unsigned r = v.u + 0x7fffu + ((v.u >> 16) & 1u);
    return (unsigned short)(r >> 16);
}
__device__ __forceinline__ float bf2f(unsigned short h) {
    union { unsigned u; float f; } v; v.u = ((unsigned)h) << 16;
    return v.f;
}

// ---------------- Kernel 0: prep ----------------
// blk 0..63 (init i): w2 -> wswz[i][tap][co32][cin16], w1 -> w1bf[i][co16][32pad],
//   w3 -> w3l[i][o10][lane64][slot8] permuted for mega's in-register pool layout:
//   lane l = h*32+co, slot s = py*2+d  ->  feature f = co*16 + py*4 + 2h + d.
// blk 64..191 (img j=blk-64): im2col -> Bmat[j][576 c][32 k] bf16,
//   c = pp*4+q, pp = py*12+px, q = dy*2+dx, k = ky*5+kx.
__global__ __launch_bounds__(256) void prep_kernel(
        const float* __restrict__ params,
        const float* __restrict__ batch,
        unsigned short* __restrict__ wswz,
        unsigned short* __restrict__ w3l,
        unsigned short* __restrict__ w1bf,
        unsigned short* __restrict__ Bmat) {
    int blk = blockIdx.x;
    int t = threadIdx.x;
    if (blk < 64) {
        int i = blk;
        const float* w2 = params + (size_t)i * P_TOTAL + 416;   // [co32][cin16][5][5]
        unsigned short* dst = wswz + (size_t)i * 12800;
        for (int k = t; k < 12800; k += 256) {
            int co = k / 400;
            int r = k - co * 400;
            int cin = r / 25;
            int s = r - cin * 25;   // s = ky*5+kx
            dst[(s * 32 + co) * 16 + cin] = f2bf(w2[k]);
        }
        const float* w3 = params + (size_t)i * P_TOTAL + 13248;  // [o10][f512]
        unsigned short* d3 = w3l + (size_t)i * 5120;
        for (int k = t; k < 5120; k += 256) {
            int o = k >> 9, r = k & 511;
            int l = r >> 3, s = r & 7;
            int co = l & 31, h = l >> 5;
            int py = s >> 1, d = s & 1;
            d3[k] = f2bf(w3[o * 512 + co * 16 + py * 4 + 2 * h + d]);
        }
        const float* w1 = params + (size_t)i * P_TOTAL;          // [co16][25]
        unsigned short* d1 = w1bf + (size_t)i * 512;
        for (int e = t; e < 512; e += 256) {
            int m = e >> 5, k = e & 31;
            d1[e] = (k < 25) ? f2bf(w1[m * 25 + k]) : (unsigned short)0;
        }
    } else {
        __shared__ float img[784];
        int j = blk - 64;
        const float* ip = batch + j * 784;
        for (int k = t; k < 784; k += 256) img[k] = ip[k];
        __syncthreads();
        unsigned short* dst = Bmat + (size_t)j * 18432;
        for (int task = t; task < 2304; task += 256) {
            int c = task >> 2, kh = task & 3;
            int pp = c >> 2, q = c & 3;
            int py = pp / 12, px = pp - py * 12;
            int y0 = 2 * py + (q >> 1);
            int x0 = 2 * px + (q & 1);
            unsigned short ov[8] __attribute__((aligned(16)));
#pragma unroll
            for (int u = 0; u < 8; ++u) {
                int k = kh * 8 + u;
                float v = 0.f;
                if (k < 25) {
                    int ky = k / 5, kx = k - ky * 5;
                    v = img[(y0 + ky) * 28 + x0 + kx];
                }
                ov[u] = f2bf(v);
            }
            *(uint4*)(dst + c * 32 + kh * 8) = *(const uint4*)ov;
        }
    }
}

// ---------------- Kernel 1 (mega): conv1 + conv2 + pool + dense + log_softmax ----------------
// Block = (init i, image-group g of 4), 4 waves, wave w = image j = g*4+w.
// R12 (= R11 with tap-stride fix): wswz staged ONCE per block into LDS
// (XOR-swizzled 16B chunks; tap block = 512 elems = 64 chunks). Phase B's 25
// per-tap weight loads become pipelined ds_reads. ONE barrier (A->B).
// LDS 53,248 B -> 3 blocks/CU. Dispatch swizzle kept (i fast, g slow).
#define A1_PIX_STRIDE 24        // elems (48 B)
#define IMG_LDS (144 * A1_PIX_STRIDE)   // 3456 elems = 6912 B per image
__global__ __launch_bounds__(256, 3) void mega_kernel(
        const float* __restrict__ params,
        const unsigned short* __restrict__ Bmat,   // [img][576][32] bf16 im2col
        const unsigned short* __restrict__ w1bf,   // [init][16][32] bf16
        const unsigned short* __restrict__ wswz,   // [init][25][32][16] bf16
        const unsigned short* __restrict__ w3l,    // [init][10][64][8] bf16 (permuted)
        float* __restrict__ out) {                 // [init][img][10] f32
    __shared__ unsigned short a1s[4 * IMG_LDS];    // 27648 B
    __shared__ unsigned short wlds[12800];         // 25600 B (total 53248 B)
    int b = blockIdx.x;
    int i = b & 63;           // init  (fast dim)
    int g = b >> 6;           // image group (slow dim)
    int t = threadIdx.x;
    int w = t >> 6;           // wave = image index within group
    int lane = t & 63;
    int j = g * 4 + w;

    // ---- stage wswz -> wlds, XOR-swizzled 16B chunks (c' = c ^ (c>>3)) ----
    // each tap = 512 elems = 64 chunks; chunk c of tap lands at tap*64 + (c^(c>>3)).
    {
        const uint4* src = (const uint4*)(wswz + (size_t)i * 12800);
        uint4* dst = (uint4*)wlds;
        for (int k = t; k < 1600; k += 256) {
            int tap = k >> 6, c = k & 63;
            int cs = c ^ ((c >> 3) & 7);
            dst[tap * 64 + cs] = src[k];
        }
    }

    // ---- Phase A: conv1 for (init i, image j), output -> own a1s slice ----
    {
        int co = lane & 15;       // conv1 out-channel = conv2 cin
        int h4 = lane >> 4;       // pool-quad row group
        short8 wfr = *(const short8*)(w1bf + (size_t)i * 512 + co * 32 + h4 * 8);
        float bias1 = params[(size_t)i * P_TOTAL + 400 + co];
        unsigned short* dst = a1s + w * IMG_LDS;
        const unsigned short* bsrc = Bmat + (size_t)j * 18432;
#pragma unroll 9
        for (int nt = 0; nt < 36; ++nt) {
            short8 afr = *(const short8*)(bsrc + (nt * 16 + co) * 32 + h4 * 8);
            float4v acc = {0.f, 0.f, 0.f, 0.f};
            acc = __builtin_amdgcn_mfma_f32_16x16x32_bf16(afr, wfr, acc, 0, 0, 0);
            float v = fmaxf(fmaxf(acc[0], acc[1]), fmaxf(acc[2], acc[3]));
            v = fmaxf(v + bias1, 0.f);
            dst[(nt * 4 + h4) * A1_PIX_STRIDE + co] = f2bf(v);   // pix = nt*4+h4
        }
    }
    __syncthreads();   // wlds visible to all waves (a1s is same-wave anyway)

    // ---- Phase B: conv2, A = pixels (a1s), B = out-channels (wlds) ----
    int n = lane & 31;        // A row = pixel ; B col = co
    int h = lane >> 5;        // k-half
    int cch = n * 2 + h;      // this lane's chunk within a tap block
    int ccs = cch ^ ((cch >> 3) & 7);
    const short8* wg = (const short8*)(wlds + ccs * 8);   // tap stride = 64 short8
    int y0 = n >> 3, x0 = n & 7;
    const unsigned short* bbase = a1s + w * IMG_LDS;
    const short8* pptr0 = (const short8*)(bbase + ((y0    ) * 12 + x0) * A1_PIX_STRIDE + h * 8);
    const short8* pptr1 = (const short8*)(bbase + ((y0 + 4) * 12 + x0) * A1_PIX_STRIDE + h * 8);

    float16 acc0 = {};   // D rows = pixels 0..31 (y 0..3), cols = co
    float16 acc1 = {};   // D rows = pixels 32..63 (y 4..7)
#pragma unroll
    for (int ky = 0; ky < 5; ++ky) {
#pragma unroll
        for (int kx = 0; kx < 5; ++kx) {
            int tap = ky * 5 + kx;
            short8 wf = wg[tap * 64];               // +tap*512 elems (LDS)
            int bo = (ky * 12 + kx) * 3;
            short8 p0 = pptr0[bo];
            short8 p1 = pptr1[bo];
            acc0 = __builtin_amdgcn_mfma_f32_32x32x16_bf16(p0, wf, acc0, 0, 0, 0);
            acc1 = __builtin_amdgcn_mfma_f32_32x32x16_bf16(p1, wf, acc1, 0, 0, 0);
        }
    }

    // ---- Phase C: in-register 2x2 pool + bias + ReLU ----
    // row r = (reg&3) + 8*(reg>>2) + 4h -> pixel (y = p>>3, x = p&7).
    // pooled (pyl,d): regs {base, base+1, base+4, base+5}, base = pyl*8 + d*2.
    // lane (co = lane&31, h) ends with 8 features f = co*16 + py*4 + 2h + d,
    // slot s = py*2 + d  — matches w3l's prep permutation.
    int co2 = lane & 31;
    float bias2 = params[(size_t)i * P_TOTAL + 13216 + co2];
    float xr[8];
#pragma unroll
    for (int pyl = 0; pyl < 2; ++pyl) {
#pragma unroll
        for (int d = 0; d < 2; ++d) {
            int base = pyl * 8 + d * 2;
            float v0 = fmaxf(fmaxf(acc0[base], acc0[base + 1]),
                             fmaxf(acc0[base + 4], acc0[base + 5]));
            float v1 = fmaxf(fmaxf(acc1[base], acc1[base + 1]),
                             fmaxf(acc1[base + 4], acc1[base + 5]));
            xr[pyl * 2 + d]     = fmaxf(v0 + bias2, 0.f);   // py = pyl
            xr[4 + pyl * 2 + d] = fmaxf(v1 + bias2, 0.f);   // py = 2+pyl
        }
    }

    // ---- dense (10x512) + log_softmax; w3l permuted per-lane ----
    const unsigned short* w3p = w3l + (size_t)i * 5120 + lane * 8;
    float acc[10];
#pragma unroll
    for (int o = 0; o < 10; ++o) {
        uint4 u = *(const uint4*)(w3p + o * 512);
        float a = 0.f;
        a = fmaf(xr[0], bf2f((unsigned short)(u.x & 0xffffu)), a);
        a = fmaf(xr[1], bf2f((unsigned short)(u.x >> 16)), a);
        a = fmaf(xr[2], bf2f((unsigned short)(u.y & 0xffffu)), a);
        a = fmaf(xr[3], bf2f((unsigned short)(u.y >> 16)), a);
        a = fmaf(xr[4], bf2f((unsigned short)(u.z & 0xffffu)), a);
        a = fmaf(xr[5], bf2f((unsigned short)(u.z >> 16)), a);
        a = fmaf(xr[6], bf2f((unsigned short)(u.w & 0xffffu)), a);
        a = fmaf(xr[7], bf2f((unsigned short)(u.w >> 16)), a);
#pragma unroll
        for (int d = 32; d >= 1; d >>= 1) a += __shfl_xor(a, d, 64);
        acc[o] = a;
    }
    const float* bp = params + (size_t)i * P_TOTAL + 18368;
    float m = -3.4e38f;
#pragma unroll
    for (int o = 0; o < 10; ++o) { acc[o] += bp[o]; m = fmaxf(m, acc[o]); }
    float ssum = 0.f;
#pragma unroll
    for (int o = 0; o < 10; ++o) ssum += expf(acc[o] - m);
    float ls = logf(ssum) + m;
    if (lane == 0) {
        float* op = out + ((size_t)i * 128 + j) * 10;
#pragma unroll
        for (int o = 0; o < 10; ++o) op[o] = acc[o] - ls;
    }
}

extern "C" void kernel_launch(void* const* d_in, const int* in_sizes, int n_in,
                              void* d_out, int out_size, void* d_ws, size_t ws_size,
                              hipStream_t stream) {
    const float* params = (const float*)d_in[0];   // (64, 18378) fp32
    const float* batch  = (const float*)d_in[1];   // (128, 1, 28, 28) fp32
    float* out = (float*)d_out;                    // (64, 128, 10) fp32

    // workspace: wswz 1,638,400 B ; w3l 655,360 B ; w1bf 65,536 B ; Bmat 4,718,592 B
    unsigned short* wswz = (unsigned short*)d_ws;
    unsigned short* w3l  = wswz + (size_t)64 * 12800;
    unsigned short* w1bf = w3l + (size_t)64 * 5120;
    unsigned short* Bmat = w1bf + (size_t)64 * 512;

    prep_kernel<<<192, 256, 0, stream>>>(params, batch, wswz, w3l, w1bf, Bmat);
    mega_kernel<<<2048, 256, 0, stream>>>(params, Bmat, w1bf, wswz, w3l, out);
}

// Round 13
// 105.098 us; speedup vs baseline: 1.0196x; 1.0196x over previous
//
#include <hip/hip_runtime.h>
#include <hip/hip_bf16.h>
#include <math.h>

// Problem constants
#define P_TOTAL 18378
// param breakpoints (floats): w1 [0,400), b1 [400,416), w2 [416,13216),
// b2 [13216,13248), w3 [13248,18368), b3 [18368,18378)

typedef __attribute__((ext_vector_type(8))) short short8;
typedef __attribute__((ext_vector_type(4))) float float4v;
typedef __attribute__((ext_vector_type(16))) float float16;

__device__ __forceinline__ unsigned short f2bf(float f) {
    union { float f; unsigned u; } v; v.f = f;
    unsigned r = v.u + 0x7fffu + ((v.u >> 16) & 1u);
    return (unsigned short)(r >> 16);
}
__device__ __forceinline__ float bf2f(unsigned short h) {
    union { unsigned u; float f; } v; v.u = ((unsigned)h) << 16;
    return v.f;
}

// ---------------- Kernel 0: prep ----------------
// blk 0..63 (init i): w2 -> wswz[i][tap][co32][cin16] bf16, w1 -> w1bf[i][co16][32pad] bf16,
//   w3 -> w3lf[i][o10][lane64][slot8] FP32, permuted for mega's in-register pool:
//   lane l = h*32+co, slot s = py*2+d  ->  feature f = co*16 + py*4 + 2h + d.
// blk 64..191 (img j=blk-64): im2col -> Bmat[j][576 c][32 k] bf16,
//   c = pp*4+q, pp = py*12+px, q = dy*2+dx, k = ky*5+kx.
__global__ __launch_bounds__(256) void prep_kernel(
        const float* __restrict__ params,
        const float* __restrict__ batch,
        unsigned short* __restrict__ wswz,
        float* __restrict__ w3lf,
        unsigned short* __restrict__ w1bf,
        unsigned short* __restrict__ Bmat) {
    int blk = blockIdx.x;
    int t = threadIdx.x;
    if (blk < 64) {
        int i = blk;
        const float* w2 = params + (size_t)i * P_TOTAL + 416;   // [co32][cin16][5][5]
        unsigned short* dst = wswz + (size_t)i * 12800;
        for (int k = t; k < 12800; k += 256) {
            int co = k / 400;
            int r = k - co * 400;
            int cin = r / 25;
            int s = r - cin * 25;   // s = ky*5+kx
            dst[(s * 32 + co) * 16 + cin] = f2bf(w2[k]);
        }
        const float* w3 = params + (size_t)i * P_TOTAL + 13248;  // [o10][f512]
        float* d3 = w3lf + (size_t)i * 5120;
        for (int k = t; k < 5120; k += 256) {
            int o = k >> 9, r = k & 511;
            int l = r >> 3, s = r & 7;
            int co = l & 31, h = l >> 5;
            int py = s >> 1, d = s & 1;
            d3[k] = w3[o * 512 + co * 16 + py * 4 + 2 * h + d];
        }
        const float* w1 = params + (size_t)i * P_TOTAL;          // [co16][25]
        unsigned short* d1 = w1bf + (size_t)i * 512;
        for (int e = t; e < 512; e += 256) {
            int m = e >> 5, k = e & 31;
            d1[e] = (k < 25) ? f2bf(w1[m * 25 + k]) : (unsigned short)0;
        }
    } else {
        __shared__ float img[784];
        int j = blk - 64;
        const float* ip = batch + j * 784;
        for (int k = t; k < 784; k += 256) img[k] = ip[k];
        __syncthreads();
        unsigned short* dst = Bmat + (size_t)j * 18432;
        for (int task = t; task < 2304; task += 256) {
            int c = task >> 2, kh = task & 3;
            int pp = c >> 2, q = c & 3;
            int py = pp / 12, px = pp - py * 12;
            int y0 = 2 * py + (q >> 1);
            int x0 = 2 * px + (q & 1);
            unsigned short ov[8] __attribute__((aligned(16)));
#pragma unroll
            for (int u = 0; u < 8; ++u) {
                int k = kh * 8 + u;
                float v = 0.f;
                if (k < 25) {
                    int ky = k / 5, kx = k - ky * 5;
                    v = img[(y0 + ky) * 28 + x0 + kx];
                }
                ov[u] = f2bf(v);
            }
            *(uint4*)(dst + c * 32 + kh * 8) = *(const uint4*)ov;
        }
    }
}

// ---------------- Kernel 1 (mega): conv1 + conv2 + pool + dense + log_softmax ----------------
// Block = (init i, image-group g of 4), 4 waves, wave w = image j = g*4+w.
// R13: revert R12's LDS weight staging (global/L2 reads, 5 blocks/CU), dense
// weights in FP32 (no bf2f unpacks), fast __expf/__logf. BARRIER-FREE.
// Dispatch swizzle kept (i fast, g slow).
#define A1_PIX_STRIDE 24        // elems (48 B)
#define IMG_LDS (144 * A1_PIX_STRIDE)   // 3456 elems = 6912 B per image
__global__ __launch_bounds__(256, 5) void mega_kernel(
        const float* __restrict__ params,
        const unsigned short* __restrict__ Bmat,   // [img][576][32] bf16 im2col
        const unsigned short* __restrict__ w1bf,   // [init][16][32] bf16
        const unsigned short* __restrict__ wswz,   // [init][25][32][16] bf16
        const float* __restrict__ w3lf,            // [init][10][64][8] f32 (permuted)
        float* __restrict__ out) {                 // [init][img][10] f32
    __shared__ unsigned short a1s[4 * IMG_LDS];    // 27648 B
    int b = blockIdx.x;
    int i = b & 63;           // init  (fast dim -> XCD-local weight residency)
    int g = b >> 6;           // image group (slow dim -> cross-XCD Bmat sharing)
    int t = threadIdx.x;
    int w = t >> 6;           // wave = image index within group
    int lane = t & 63;
    int j = g * 4 + w;

    // ---- Phase A: conv1 for (init i, image j), output -> own a1s slice ----
    {
        int co = lane & 15;       // conv1 out-channel = conv2 cin
        int h4 = lane >> 4;       // pool-quad row group
        short8 wfr = *(const short8*)(w1bf + (size_t)i * 512 + co * 32 + h4 * 8);
        float bias1 = params[(size_t)i * P_TOTAL + 400 + co];
        unsigned short* dst = a1s + w * IMG_LDS;
        const unsigned short* bsrc = Bmat + (size_t)j * 18432;
#pragma unroll 6
        for (int nt = 0; nt < 36; ++nt) {
            short8 afr = *(const short8*)(bsrc + (nt * 16 + co) * 32 + h4 * 8);
            float4v acc = {0.f, 0.f, 0.f, 0.f};
            acc = __builtin_amdgcn_mfma_f32_16x16x32_bf16(afr, wfr, acc, 0, 0, 0);
            float v = fmaxf(fmaxf(acc[0], acc[1]), fmaxf(acc[2], acc[3]));
            v = fmaxf(v + bias1, 0.f);
            dst[(nt * 4 + h4) * A1_PIX_STRIDE + co] = f2bf(v);   // pix = nt*4+h4
        }
    }
    // no barrier: this wave reads only its own writes (DS program order)

    // ---- Phase B: conv2, A = pixels (a1s), B = out-channels (wswz, global/L2) ----
    int n = lane & 31;        // A row = pixel ; B col = co
    int h = lane >> 5;        // k-half
    const short8* wg = (const short8*)(wswz + (size_t)i * 12800 + n * 16 + h * 8);
    int y0 = n >> 3, x0 = n & 7;
    const unsigned short* bbase = a1s + w * IMG_LDS;
    const short8* pptr0 = (const short8*)(bbase + ((y0    ) * 12 + x0) * A1_PIX_STRIDE + h * 8);
    const short8* pptr1 = (const short8*)(bbase + ((y0 + 4) * 12 + x0) * A1_PIX_STRIDE + h * 8);

    float16 acc0 = {};   // D rows = pixels 0..31 (y 0..3), cols = co
    float16 acc1 = {};   // D rows = pixels 32..63 (y 4..7)
#pragma unroll
    for (int ky = 0; ky < 5; ++ky) {
#pragma unroll
        for (int kx = 0; kx < 5; ++kx) {
            int tap = ky * 5 + kx;
            short8 wf = wg[tap * 64];               // +tap*1024 B (global, L2)
            int bo = (ky * 12 + kx) * 3;
            short8 p0 = pptr0[bo];
            short8 p1 = pptr1[bo];
            acc0 = __builtin_amdgcn_mfma_f32_32x32x16_bf16(p0, wf, acc0, 0, 0, 0);
            acc1 = __builtin_amdgcn_mfma_f32_32x32x16_bf16(p1, wf, acc1, 0, 0, 0);
        }
    }

    // ---- Phase C: in-register 2x2 pool + bias + ReLU ----
    // row r = (reg&3) + 8*(reg>>2) + 4h -> pixel (y = p>>3, x = p&7).
    // pooled (pyl,d): regs {base, base+1, base+4, base+5}, base = pyl*8 + d*2.
    // lane (co = lane&31, h) ends with 8 features f = co*16 + py*4 + 2h + d,
    // slot s = py*2 + d  — matches w3lf's prep permutation.
    int co2 = lane & 31;
    float bias2 = params[(size_t)i * P_TOTAL + 13216 + co2];
    float xr[8];
#pragma unroll
    for (int pyl = 0; pyl < 2; ++pyl) {
#pragma unroll
        for (int d = 0; d < 2; ++d) {
            int base = pyl * 8 + d * 2;
            float v0 = fmaxf(fmaxf(acc0[base], acc0[base + 1]),
                             fmaxf(acc0[base + 4], acc0[base + 5]));
            float v1 = fmaxf(fmaxf(acc1[base], acc1[base + 1]),
                             fmaxf(acc1[base + 4], acc1[base + 5]));
            xr[pyl * 2 + d]     = fmaxf(v0 + bias2, 0.f);   // py = pyl
            xr[4 + pyl * 2 + d] = fmaxf(v1 + bias2, 0.f);   // py = 2+pyl
        }
    }

    // ---- dense (10x512) + log_softmax; w3lf f32 permuted per-lane (no unpacks) ----
    const float* w3p = w3lf + (size_t)i * 5120 + lane * 8;
    float acc[10];
#pragma unroll
    for (int o = 0; o < 10; ++o) {
        float4v u0 = *(const float4v*)(w3p + o * 512);
        float4v u1 = *(const float4v*)(w3p + o * 512 + 4);
        float a = 0.f;
        a = fmaf(xr[0], u0[0], a);
        a = fmaf(xr[1], u0[1], a);
        a = fmaf(xr[2], u0[2], a);
        a = fmaf(xr[3], u0[3], a);
        a = fmaf(xr[4], u1[0], a);
        a = fmaf(xr[5], u1[1], a);
        a = fmaf(xr[6], u1[2], a);
        a = fmaf(xr[7], u1[3], a);
#pragma unroll
        for (int d = 32; d >= 1; d >>= 1) a += __shfl_xor(a, d, 64);
        acc[o] = a;
    }
    const float* bp = params + (size_t)i * P_TOTAL + 18368;
    float m = -3.4e38f;
#pragma unroll
    for (int o = 0; o < 10; ++o) { acc[o] += bp[o]; m = fmaxf(m, acc[o]); }
    float ssum = 0.f;
#pragma unroll
    for (int o = 0; o < 10; ++o) ssum += __expf(acc[o] - m);
    float ls = __logf(ssum) + m;
    if (lane == 0) {
        float* op = out + ((size_t)i * 128 + j) * 10;
#pragma unroll
        for (int o = 0; o < 10; ++o) op[o] = acc[o] - ls;
    }
}

extern "C" void kernel_launch(void* const* d_in, const int* in_sizes, int n_in,
                              void* d_out, int out_size, void* d_ws, size_t ws_size,
                              hipStream_t stream) {
    const float* params = (const float*)d_in[0];   // (64, 18378) fp32
    const float* batch  = (const float*)d_in[1];   // (128, 1, 28, 28) fp32
    float* out = (float*)d_out;                    // (64, 128, 10) fp32

    // workspace (16B-aligned sections):
    //   wswz 64*12800 bf16 = 1,638,400 B
    //   w3lf 64*5120  f32  = 1,310,720 B
    //   w1bf 64*512   bf16 =    65,536 B
    //   Bmat 128*18432 bf16 = 4,718,592 B
    unsigned short* wswz = (unsigned short*)d_ws;
    float* w3lf = (float*)((char*)d_ws + 1638400);
    unsigned short* w1bf = (unsigned short*)((char*)d_ws + 1638400 + 1310720);
    unsigned short* Bmat = (unsigned short*)((char*)d_ws + 1638400 + 1310720 + 65536);

    prep_kernel<<<192, 256, 0, stream>>>(params, batch, wswz, w3lf, w1bf, Bmat);
    mega_kernel<<<2048, 256, 0, stream>>>(params, Bmat, w1bf, wswz, w3lf, out);
}